// Round 6
// baseline (166.452 us; speedup 1.0000x reference)
//
#include <hip/hip_runtime.h>
#include <stdint.h>

// ---------------------------------------------------------------------------
// UnifiedEnergyFunction: total/hopfield/consistency/regularization scalars.
//   hopfield = mean_b( -logsumexp_n( z[b,:] . M[n,:] ) )
//   consistency = mean_b ||z - z_next||^2
//   regularization = 0.01 * mean_b ||z||^2
// v6 = v5 + software-pipelined epilogue: double-state accumulator (accA/accB);
// tile t's exp2 epilogue is interleaved into tile t+1's K-loop (4 elems/kc),
// so the VALU/trans work hides under MFMA instead of serializing before the
// barrier. Memory system unchanged from v5 (proven: 24.6 MB fetch, no spill).
// ---------------------------------------------------------------------------

typedef __attribute__((ext_vector_type(8))) short short8;
typedef __attribute__((ext_vector_type(4))) float f32x4;

#define N_PAT  65536
#define D_DIM  256
#define B_ROWS 4096
#define NSPLIT 16                 // M ranges (2 per XCD, 2MB each)
#define NRANGE (N_PAT / NSPLIT)   // 4096
#define NTILE  64                 // n rows per LDS tile
#define NITER  (NRANGE / NTILE)   // 64 (even: required by the 2-tile pipeline)
#define BBLK   128                // b rows per block (2 bh x 64)
#define SHIFT2 69.0f              // fixed shift in log2 domain (~48 nats)
#define LOG2E  1.44269504f
#define LN2    0.69314718f

// workspace layout (bytes)
#define WS_M_OFF   ((size_t)0)
#define WS_M_BYTES ((size_t)N_PAT * D_DIM * 2)      // 32 MB bf16 M
#define WS_Z_OFF   (WS_M_OFF + WS_M_BYTES)
#define WS_Z_BYTES ((size_t)B_ROWS * D_DIM * 2)     // 2 MB bf16 z*log2e
#define WS_LSE_OFF (WS_Z_OFF + WS_Z_BYTES)
#define WS_LSE_BYTES ((size_t)B_ROWS * NSPLIT * 4)  // float S per (b, nsplit)
#define WS_CSS_OFF (WS_LSE_OFF + WS_LSE_BYTES)
#define WS_ZSS_OFF (WS_CSS_OFF + (size_t)512 * 4)

__device__ __forceinline__ short f2bf(float f) {
  uint32_t u = __float_as_uint(f);
  uint32_t r = (u + 0x7fffu + ((u >> 16) & 1u)) >> 16;
  return (short)(r & 0xffffu);
}

__device__ __forceinline__ float fexp2(float x) {
  return __builtin_amdgcn_exp2f(x);   // v_exp_f32 (hardware base-2 exp)
}

typedef __attribute__((address_space(3))) uint32_t lds_u32;
typedef __attribute__((address_space(1))) uint32_t glb_u32;
__device__ __forceinline__ void load_lds16(const void* g, void* l) {
  __builtin_amdgcn_global_load_lds((const glb_u32*)g, (lds_u32*)l, 16, 0, 0);
}

__device__ __forceinline__ float waveRedAdd(float v) {
  #pragma unroll
  for (int o = 32; o > 0; o >>= 1) v += __shfl_down(v, o, 64);
  return v;
}

// ---------------------------------------------------------------- kernel A1
__global__ void convert_m_kernel(const float* __restrict__ src, short* __restrict__ dst) {
  int64_t i = (int64_t)blockIdx.x * 256 + threadIdx.x;
  const int64_t n8 = (int64_t)N_PAT * D_DIM / 8;
  const int64_t stride = (int64_t)gridDim.x * 256;
  for (; i < n8; i += stride) {
    const float4 a = *(const float4*)(src + i * 8);
    const float4 b = *(const float4*)(src + i * 8 + 4);
    float v[8] = {a.x, a.y, a.z, a.w, b.x, b.y, b.z, b.w};
    short8 o;
    #pragma unroll
    for (int j = 0; j < 8; ++j) o[j] = f2bf(v[j]);
    *(short8*)(dst + i * 8) = o;
  }
}

// ---------------------------------------------------------------- kernel A2
// z -> bf16 scaled by log2(e), plus partial sums of ||z-zn||^2 and ||z||^2
__global__ void prep_z_kernel(const float* __restrict__ z, const float* __restrict__ zn,
                              short* __restrict__ zbf, float* __restrict__ css,
                              float* __restrict__ zss) {
  int t = blockIdx.x * 256 + threadIdx.x;  // 512 blocks x 256 = exactly B*D/8
  const float* az = z + (size_t)t * 8;
  const float* an = zn + (size_t)t * 8;
  float4 z0 = *(const float4*)(az), z1 = *(const float4*)(az + 4);
  float4 n0 = *(const float4*)(an), n1 = *(const float4*)(an + 4);
  float zv[8] = {z0.x, z0.y, z0.z, z0.w, z1.x, z1.y, z1.z, z1.w};
  float nv[8] = {n0.x, n0.y, n0.z, n0.w, n1.x, n1.y, n1.z, n1.w};
  short8 o;
  float cs = 0.f, zs = 0.f;
  #pragma unroll
  for (int j = 0; j < 8; ++j) {
    o[j] = f2bf(zv[j] * LOG2E);   // GEMM output lands in log2 domain
    float d = zv[j] - nv[j];
    cs += d * d;
    zs += zv[j] * zv[j];
  }
  *(short8*)(zbf + (size_t)t * 8) = o;

  __shared__ float rc[4], rz[4];
  cs = waveRedAdd(cs);
  zs = waveRedAdd(zs);
  int w = threadIdx.x >> 6, lane = threadIdx.x & 63;
  if (lane == 0) { rc[w] = cs; rz[w] = zs; }
  __syncthreads();
  if (threadIdx.x == 0) {
    css[blockIdx.x] = rc[0] + rc[1] + rc[2] + rc[3];
    zss[blockIdx.x] = rz[0] + rz[1] + rz[2] + rz[3];
  }
}

// ---------------------------------------------------------------- kernel B
// Per block: 128 b-rows x 4096-n slice; M staged 64-row tiles, double-buffered.
// 4 waves = (bh, nh): each owns 64 b (zf in 128 VGPR) x 32 n of each tile.
// Pipelined epilogue: while tile t's MFMAs fill ACC, tile t-1's exp2 (EPI set)
// issues on the VALU/trans pipe, 4 elements per kc step.
__global__ __launch_bounds__(256, 2) void lse_kernel(const short* __restrict__ Mbf,
                                                     const short* __restrict__ zbf,
                                                     float* __restrict__ lsep) {
  __shared__ short mt[2][NTILE * D_DIM];  // 2 x 32KB, rows of 512B, swizzled
  __shared__ float sums[2][BBLK];         // per-nh partial S

  const int bid = blockIdx.x;             // 512 blocks
  const int xcd = bid & 7;
  const int g = bid >> 3;                 // 0..63
  const int bblk = g & 31;
  const int half = g >> 5;
  const int nsplit = xcd * 2 + half;      // 2 ranges live per XCD (proven)

  const int tid = threadIdx.x;
  const int w = tid >> 6;
  const int lane = tid & 63;
  const int l15 = lane & 15;
  const int grp = lane >> 4;
  const int bh = w & 1;                   // b-half (64 cols)
  const int nh = w >> 1;                  // n-half of each tile (32 rows)

  const char* msrc = (const char*)(Mbf + ((size_t)nsplit * NRANGE) * D_DIM);

  // stage one 64-row M tile (32KB); linear dest, inverse-swizzled src
  auto stageM = [&](int it, int buf) {
    const char* src = msrc + (size_t)it * NTILE * D_DIM * 2;
    char* dst = (char*)&mt[buf][0];
    #pragma unroll
    for (int i = 0; i < 8; ++i) {
      int c = w * 8 + i;
      int d = c * 1024 + lane * 16;
      int s = d ^ (((d >> 9) & 7) << 4);
      load_lds16(src + s, dst + c * 1024);
    }
  };

  stageM(0, 0);

  // hoist z fragments: 4 b-subtiles x 8 k-chunks = 128 VGPR (one-time, L2)
  short8 zf[4][8];
  const int brow0 = bblk * BBLK + bh * 64;
  #pragma unroll
  for (int bt = 0; bt < 4; ++bt) {
    #pragma unroll
    for (int kc = 0; kc < 8; ++kc) {
      int row = brow0 + bt * 16 + l15;
      zf[bt][kc] = *(const short8*)(zbf + (size_t)row * D_DIM + kc * 32 + grp * 8);
    }
  }

  __syncthreads();  // tile 0 staged

  float ssum[4] = {0.f, 0.f, 0.f, 0.f};
  int cur = 0;
  int it = 0;

  f32x4 accA[2][4], accB[2][4];
  // accB starts at -inf: its first (dummy) epilogue contributes exp2(-inf)=0.
  #pragma unroll
  for (int ns = 0; ns < 2; ++ns)
    #pragma unroll
    for (int bt = 0; bt < 4; ++bt)
      #pragma unroll
      for (int q = 0; q < 4; ++q) accB[ns][bt][q] = -INFINITY;

  // tile body: MFMAs into ACC, interleaved exp2-epilogue of EPI (prev tile)
  auto tileBody = [&](f32x4 (&ACC)[2][4], f32x4 (&EPI)[2][4]) {
    if (it + 1 < NITER) stageM(it + 1, cur ^ 1);  // prefetch next tile

    #pragma unroll
    for (int ns = 0; ns < 2; ++ns)
      #pragma unroll
      for (int bt = 0; bt < 4; ++bt)
        #pragma unroll
        for (int q = 0; q < 4; ++q) ACC[ns][bt][q] = -SHIFT2;

    const char* tile = (const char*)&mt[cur][0];
    #pragma unroll
    for (int kc = 0; kc < 8; ++kc) {
      short8 mf[2];
      #pragma unroll
      for (int ns = 0; ns < 2; ++ns) {
        int row = nh * 32 + ns * 16 + l15;
        int a = (row * 512 + kc * 64 + grp * 16) ^ ((row & 7) << 4);
        mf[ns] = *(const short8*)(tile + a);
      }
      #pragma unroll
      for (int ns = 0; ns < 2; ++ns)
        #pragma unroll
        for (int bt = 0; bt < 4; ++bt)
          ACC[ns][bt] = __builtin_amdgcn_mfma_f32_16x16x32_bf16(mf[ns], zf[bt][kc],
                                                                ACC[ns][bt], 0, 0, 0);
      // interleaved epilogue: 4 elements of the PREVIOUS tile's acc per kc
      #pragma unroll
      for (int j = 0; j < 4; ++j) {
        int e = kc * 4 + j;                 // 0..31, all indices compile-time
        ssum[(e >> 2) & 3] += fexp2(EPI[e >> 4][(e >> 2) & 3][e & 3]);
      }
    }

    __syncthreads();  // all waves done with cur; next tile fully staged
    cur ^= 1;
    ++it;
  };

  for (int itp = 0; itp < NITER / 2; ++itp) {
    tileBody(accA, accB);   // even tile: compute A, drain B
    tileBody(accB, accA);   // odd tile:  compute B, drain A
  }

  // drain the final tile's accumulator (accB was computed last)
  #pragma unroll
  for (int e = 0; e < 32; ++e)
    ssum[(e >> 2) & 3] += fexp2(accB[e >> 4][(e >> 2) & 3][e & 3]);

  // reduce: 4 lane-groups hold different n-rows for the same b-col
  #pragma unroll
  for (int bt = 0; bt < 4; ++bt) {
    ssum[bt] += __shfl_xor(ssum[bt], 16, 64);
    ssum[bt] += __shfl_xor(ssum[bt], 32, 64);
  }
  if (grp == 0) {
    #pragma unroll
    for (int bt = 0; bt < 4; ++bt) sums[nh][bh * 64 + bt * 16 + l15] = ssum[bt];
  }
  __syncthreads();
  if (tid < BBLK) {
    lsep[(size_t)(bblk * BBLK + tid) * NSPLIT + nsplit] = sums[0][tid] + sums[1][tid];
  }
}

// ---------------------------------------------------------------- kernel C
__global__ void finalize_kernel(const float* __restrict__ lsep, const float* __restrict__ css,
                                const float* __restrict__ zss, float* __restrict__ out) {
  __shared__ float r1[16], r2[16], r3[16];
  int tid = threadIdx.x;  // 1024
  float sum_lse = 0.f;
  for (int r = tid; r < B_ROWS; r += 1024) {
    float S = 0.f;
    #pragma unroll
    for (int i = 0; i < NSPLIT; ++i) S += lsep[(size_t)r * NSPLIT + i];
    sum_lse += SHIFT2 * LN2 + logf(S);   // back to nats
  }
  float cs = 0.f, zs = 0.f;
  if (tid < 512) { cs = css[tid]; zs = zss[tid]; }

  sum_lse = waveRedAdd(sum_lse);
  cs = waveRedAdd(cs);
  zs = waveRedAdd(zs);
  int w = tid >> 6, lane = tid & 63;
  if (lane == 0) { r1[w] = sum_lse; r2[w] = cs; r3[w] = zs; }
  __syncthreads();
  if (tid == 0) {
    float sl = 0.f, sc = 0.f, sz = 0.f;
    #pragma unroll
    for (int i = 0; i < 16; ++i) { sl += r1[i]; sc += r2[i]; sz += r3[i]; }
    float hop = -sl / (float)B_ROWS;
    float cons = sc / (float)B_ROWS;
    float reg = 0.01f * sz / (float)B_ROWS;
    out[0] = hop + cons + reg;
    out[1] = hop;
    out[2] = cons;
    out[3] = reg;
  }
}

// ---------------------------------------------------------------------------
extern "C" void kernel_launch(void* const* d_in, const int* in_sizes, int n_in,
                              void* d_out, int out_size, void* d_ws, size_t ws_size,
                              hipStream_t stream) {
  (void)in_sizes; (void)n_in; (void)out_size; (void)ws_size;
  const float* z  = (const float*)d_in[0];
  const float* zn = (const float*)d_in[1];
  const float* M  = (const float*)d_in[2];
  char* ws = (char*)d_ws;
  short* Mbf = (short*)(ws + WS_M_OFF);
  short* zbf = (short*)(ws + WS_Z_OFF);
  float* lsep = (float*)(ws + WS_LSE_OFF);
  float* css = (float*)(ws + WS_CSS_OFF);
  float* zss = (float*)(ws + WS_ZSS_OFF);

  convert_m_kernel<<<2048, 256, 0, stream>>>(M, Mbf);
  prep_z_kernel<<<512, 256, 0, stream>>>(z, zn, zbf, css, zss);
  lse_kernel<<<512, 256, 0, stream>>>(Mbf, zbf, lsep);
  finalize_kernel<<<1, 1024, 0, stream>>>(lsep, css, zss, (float*)d_out);
}

// Round 7
// 148.252 us; speedup vs baseline: 1.1228x; 1.1228x over previous
//
#include <hip/hip_runtime.h>
#include <stdint.h>

// ---------------------------------------------------------------------------
// UnifiedEnergyFunction: total/hopfield/consistency/regularization scalars.
//   hopfield = mean_b( -logsumexp_n( z[b,:] . M[n,:] ) )
//   consistency = mean_b ||z - z_next||^2
//   regularization = 0.01 * mean_b ||z||^2
// v7 = v5 (141 us, proven memory system: 24.6 MB fetch, no spill)
//   + one-kc-ahead LDS fragment prefetch (hide ~150cy ds_read latency
//     under the previous kc's MFMAs; named regs, no dynamic indexing)
//   + s_setprio(1) around the MFMA cluster (2 unsynced blocks/CU ->
//     phase diversity; T5-positive regime).
// v6's double-acc interleaved epilogue REVERTED (spilled, -12%).
// ---------------------------------------------------------------------------

typedef __attribute__((ext_vector_type(8))) short short8;
typedef __attribute__((ext_vector_type(4))) float f32x4;

#define N_PAT  65536
#define D_DIM  256
#define B_ROWS 4096
#define NSPLIT 16                 // M ranges (2 per XCD, 2MB each)
#define NRANGE (N_PAT / NSPLIT)   // 4096
#define NTILE  64                 // n rows per LDS tile
#define NITER  (NRANGE / NTILE)   // 64
#define BBLK   128                // b rows per block (2 bh x 64)
#define SHIFT2 69.0f              // fixed shift in log2 domain (~48 nats)
#define LOG2E  1.44269504f
#define LN2    0.69314718f

// workspace layout (bytes)
#define WS_M_OFF   ((size_t)0)
#define WS_M_BYTES ((size_t)N_PAT * D_DIM * 2)      // 32 MB bf16 M
#define WS_Z_OFF   (WS_M_OFF + WS_M_BYTES)
#define WS_Z_BYTES ((size_t)B_ROWS * D_DIM * 2)     // 2 MB bf16 z*log2e
#define WS_LSE_OFF (WS_Z_OFF + WS_Z_BYTES)
#define WS_LSE_BYTES ((size_t)B_ROWS * NSPLIT * 4)  // float S per (b, nsplit)
#define WS_CSS_OFF (WS_LSE_OFF + WS_LSE_BYTES)
#define WS_ZSS_OFF (WS_CSS_OFF + (size_t)512 * 4)

__device__ __forceinline__ short f2bf(float f) {
  uint32_t u = __float_as_uint(f);
  uint32_t r = (u + 0x7fffu + ((u >> 16) & 1u)) >> 16;
  return (short)(r & 0xffffu);
}

__device__ __forceinline__ float fexp2(float x) {
  return __builtin_amdgcn_exp2f(x);   // v_exp_f32 (hardware base-2 exp)
}

typedef __attribute__((address_space(3))) uint32_t lds_u32;
typedef __attribute__((address_space(1))) uint32_t glb_u32;
__device__ __forceinline__ void load_lds16(const void* g, void* l) {
  __builtin_amdgcn_global_load_lds((const glb_u32*)g, (lds_u32*)l, 16, 0, 0);
}

__device__ __forceinline__ float waveRedAdd(float v) {
  #pragma unroll
  for (int o = 32; o > 0; o >>= 1) v += __shfl_down(v, o, 64);
  return v;
}

// ---------------------------------------------------------------- kernel A1
__global__ void convert_m_kernel(const float* __restrict__ src, short* __restrict__ dst) {
  int64_t i = (int64_t)blockIdx.x * 256 + threadIdx.x;
  const int64_t n8 = (int64_t)N_PAT * D_DIM / 8;
  const int64_t stride = (int64_t)gridDim.x * 256;
  for (; i < n8; i += stride) {
    const float4 a = *(const float4*)(src + i * 8);
    const float4 b = *(const float4*)(src + i * 8 + 4);
    float v[8] = {a.x, a.y, a.z, a.w, b.x, b.y, b.z, b.w};
    short8 o;
    #pragma unroll
    for (int j = 0; j < 8; ++j) o[j] = f2bf(v[j]);
    *(short8*)(dst + i * 8) = o;
  }
}

// ---------------------------------------------------------------- kernel A2
// z -> bf16 scaled by log2(e), plus partial sums of ||z-zn||^2 and ||z||^2
__global__ void prep_z_kernel(const float* __restrict__ z, const float* __restrict__ zn,
                              short* __restrict__ zbf, float* __restrict__ css,
                              float* __restrict__ zss) {
  int t = blockIdx.x * 256 + threadIdx.x;  // 512 blocks x 256 = exactly B*D/8
  const float* az = z + (size_t)t * 8;
  const float* an = zn + (size_t)t * 8;
  float4 z0 = *(const float4*)(az), z1 = *(const float4*)(az + 4);
  float4 n0 = *(const float4*)(an), n1 = *(const float4*)(an + 4);
  float zv[8] = {z0.x, z0.y, z0.z, z0.w, z1.x, z1.y, z1.z, z1.w};
  float nv[8] = {n0.x, n0.y, n0.z, n0.w, n1.x, n1.y, n1.z, n1.w};
  short8 o;
  float cs = 0.f, zs = 0.f;
  #pragma unroll
  for (int j = 0; j < 8; ++j) {
    o[j] = f2bf(zv[j] * LOG2E);   // GEMM output lands in log2 domain
    float d = zv[j] - nv[j];
    cs += d * d;
    zs += zv[j] * zv[j];
  }
  *(short8*)(zbf + (size_t)t * 8) = o;

  __shared__ float rc[4], rz[4];
  cs = waveRedAdd(cs);
  zs = waveRedAdd(zs);
  int w = threadIdx.x >> 6, lane = threadIdx.x & 63;
  if (lane == 0) { rc[w] = cs; rz[w] = zs; }
  __syncthreads();
  if (threadIdx.x == 0) {
    css[blockIdx.x] = rc[0] + rc[1] + rc[2] + rc[3];
    zss[blockIdx.x] = rz[0] + rz[1] + rz[2] + rz[3];
  }
}

// ---------------------------------------------------------------- kernel B
// Per block: 128 b-rows x 4096-n slice; M staged 64-row tiles, double-buffered.
// 4 waves = (bh, nh): each owns 64 b (zf in 128 AGPR/VGPR) x 32 n of each tile.
// K-loop is 1-deep software-pipelined: kc+1's ds_reads issue before kc's MFMAs.
__global__ __launch_bounds__(256, 2) void lse_kernel(const short* __restrict__ Mbf,
                                                     const short* __restrict__ zbf,
                                                     float* __restrict__ lsep) {
  __shared__ short mt[2][NTILE * D_DIM];  // 2 x 32KB, rows of 512B, swizzled
  __shared__ float sums[2][BBLK];         // per-nh partial S

  const int bid = blockIdx.x;             // 512 blocks
  const int xcd = bid & 7;
  const int g = bid >> 3;                 // 0..63
  const int bblk = g & 31;
  const int half = g >> 5;
  const int nsplit = xcd * 2 + half;      // 2 ranges live per XCD (proven)

  const int tid = threadIdx.x;
  const int w = tid >> 6;
  const int lane = tid & 63;
  const int l15 = lane & 15;
  const int grp = lane >> 4;
  const int bh = w & 1;                   // b-half (64 cols)
  const int nh = w >> 1;                  // n-half of each tile (32 rows)

  const char* msrc = (const char*)(Mbf + ((size_t)nsplit * NRANGE) * D_DIM);

  // stage one 64-row M tile (32KB); linear dest, inverse-swizzled src
  auto stageM = [&](int it, int buf) {
    const char* src = msrc + (size_t)it * NTILE * D_DIM * 2;
    char* dst = (char*)&mt[buf][0];
    #pragma unroll
    for (int i = 0; i < 8; ++i) {
      int c = w * 8 + i;
      int d = c * 1024 + lane * 16;
      int s = d ^ (((d >> 9) & 7) << 4);
      load_lds16(src + s, dst + c * 1024);
    }
  };

  stageM(0, 0);

  // hoist z fragments: 4 b-subtiles x 8 k-chunks = 128 regs (one-time, L2)
  short8 zf[4][8];
  const int brow0 = bblk * BBLK + bh * 64;
  #pragma unroll
  for (int bt = 0; bt < 4; ++bt) {
    #pragma unroll
    for (int kc = 0; kc < 8; ++kc) {
      int row = brow0 + bt * 16 + l15;
      zf[bt][kc] = *(const short8*)(zbf + (size_t)row * D_DIM + kc * 32 + grp * 8);
    }
  }

  __syncthreads();  // tile 0 staged

  float ssum[4] = {0.f, 0.f, 0.f, 0.f};
  int cur = 0;

  // loop-invariant pieces of the swizzled LDS fragment addresses
  const int arow0 = nh * 32 + 0 * 16 + l15;
  const int arow1 = nh * 32 + 1 * 16 + l15;
  const int abase0 = (arow0 * 512 + grp * 16) ^ ((arow0 & 7) << 4);
  const int abase1 = (arow1 * 512 + grp * 16) ^ ((arow1 & 7) << 4);
  // NOTE: XOR bits are 4..6 and kc*64 touches bit 6+, so kc*64 must be added
  // inside the XORed expression; recompute per kc (2 VALU ops, cheap).

  for (int it = 0; it < NITER; ++it) {
    if (it + 1 < NITER) stageM(it + 1, cur ^ 1);  // prefetch next tile

    f32x4 acc[2][4];
    #pragma unroll
    for (int ns = 0; ns < 2; ++ns)
      #pragma unroll
      for (int bt = 0; bt < 4; ++bt)
        #pragma unroll
        for (int q = 0; q < 4; ++q) acc[ns][bt][q] = -SHIFT2;

    const char* tile = (const char*)&mt[cur][0];

    // 1-deep pipelined K-loop: named current/next fragments (no dyn indexing)
    short8 mfC0, mfC1, mfN0, mfN1;
    {
      int a0 = (arow0 * 512 + 0 * 64 + grp * 16) ^ ((arow0 & 7) << 4);
      int a1 = (arow1 * 512 + 0 * 64 + grp * 16) ^ ((arow1 & 7) << 4);
      mfC0 = *(const short8*)(tile + a0);
      mfC1 = *(const short8*)(tile + a1);
    }
    #pragma unroll
    for (int kc = 0; kc < 8; ++kc) {
      if (kc + 1 < 8) {
        int a0 = (arow0 * 512 + (kc + 1) * 64 + grp * 16) ^ ((arow0 & 7) << 4);
        int a1 = (arow1 * 512 + (kc + 1) * 64 + grp * 16) ^ ((arow1 & 7) << 4);
        mfN0 = *(const short8*)(tile + a0);
        mfN1 = *(const short8*)(tile + a1);
      }
      __builtin_amdgcn_s_setprio(1);
      #pragma unroll
      for (int bt = 0; bt < 4; ++bt)
        acc[0][bt] = __builtin_amdgcn_mfma_f32_16x16x32_bf16(mfC0, zf[bt][kc],
                                                             acc[0][bt], 0, 0, 0);
      #pragma unroll
      for (int bt = 0; bt < 4; ++bt)
        acc[1][bt] = __builtin_amdgcn_mfma_f32_16x16x32_bf16(mfC1, zf[bt][kc],
                                                             acc[1][bt], 0, 0, 0);
      __builtin_amdgcn_s_setprio(0);
      mfC0 = mfN0;
      mfC1 = mfN1;
    }

    // epilogue: acc = log2-logit - SHIFT2; native exp2 + accumulate
    #pragma unroll
    for (int bt = 0; bt < 4; ++bt) {
      float s0 = 0.f, s1 = 0.f, s2 = 0.f, s3 = 0.f;
      #pragma unroll
      for (int ns = 0; ns < 2; ++ns) {
        s0 += fexp2(acc[ns][bt][0]);
        s1 += fexp2(acc[ns][bt][1]);
        s2 += fexp2(acc[ns][bt][2]);
        s3 += fexp2(acc[ns][bt][3]);
      }
      ssum[bt] += (s0 + s1) + (s2 + s3);
    }

    __syncthreads();  // all waves done with cur; next tile fully staged
    cur ^= 1;
  }

  // reduce: 4 lane-groups hold different n-rows for the same b-col
  #pragma unroll
  for (int bt = 0; bt < 4; ++bt) {
    ssum[bt] += __shfl_xor(ssum[bt], 16, 64);
    ssum[bt] += __shfl_xor(ssum[bt], 32, 64);
  }
  if (grp == 0) {
    #pragma unroll
    for (int bt = 0; bt < 4; ++bt) sums[nh][bh * 64 + bt * 16 + l15] = ssum[bt];
  }
  __syncthreads();
  if (tid < BBLK) {
    lsep[(size_t)(bblk * BBLK + tid) * NSPLIT + nsplit] = sums[0][tid] + sums[1][tid];
  }
}

// ---------------------------------------------------------------- kernel C
__global__ void finalize_kernel(const float* __restrict__ lsep, const float* __restrict__ css,
                                const float* __restrict__ zss, float* __restrict__ out) {
  __shared__ float r1[16], r2[16], r3[16];
  int tid = threadIdx.x;  // 1024
  float sum_lse = 0.f;
  for (int r = tid; r < B_ROWS; r += 1024) {
    float S = 0.f;
    #pragma unroll
    for (int i = 0; i < NSPLIT; ++i) S += lsep[(size_t)r * NSPLIT + i];
    sum_lse += SHIFT2 * LN2 + logf(S);   // back to nats
  }
  float cs = 0.f, zs = 0.f;
  if (tid < 512) { cs = css[tid]; zs = zss[tid]; }

  sum_lse = waveRedAdd(sum_lse);
  cs = waveRedAdd(cs);
  zs = waveRedAdd(zs);
  int w = tid >> 6, lane = tid & 63;
  if (lane == 0) { r1[w] = sum_lse; r2[w] = cs; r3[w] = zs; }
  __syncthreads();
  if (tid == 0) {
    float sl = 0.f, sc = 0.f, sz = 0.f;
    #pragma unroll
    for (int i = 0; i < 16; ++i) { sl += r1[i]; sc += r2[i]; sz += r3[i]; }
    float hop = -sl / (float)B_ROWS;
    float cons = sc / (float)B_ROWS;
    float reg = 0.01f * sz / (float)B_ROWS;
    out[0] = hop + cons + reg;
    out[1] = hop;
    out[2] = cons;
    out[3] = reg;
  }
}

// ---------------------------------------------------------------------------
extern "C" void kernel_launch(void* const* d_in, const int* in_sizes, int n_in,
                              void* d_out, int out_size, void* d_ws, size_t ws_size,
                              hipStream_t stream) {
  (void)in_sizes; (void)n_in; (void)out_size; (void)ws_size;
  const float* z  = (const float*)d_in[0];
  const float* zn = (const float*)d_in[1];
  const float* M  = (const float*)d_in[2];
  char* ws = (char*)d_ws;
  short* Mbf = (short*)(ws + WS_M_OFF);
  short* zbf = (short*)(ws + WS_Z_OFF);
  float* lsep = (float*)(ws + WS_LSE_OFF);
  float* css = (float*)(ws + WS_CSS_OFF);
  float* zss = (float*)(ws + WS_ZSS_OFF);

  convert_m_kernel<<<2048, 256, 0, stream>>>(M, Mbf);
  prep_z_kernel<<<512, 256, 0, stream>>>(z, zn, zbf, css, zss);
  lse_kernel<<<512, 256, 0, stream>>>(Mbf, zbf, lsep);
  finalize_kernel<<<1, 1024, 0, stream>>>(lsep, css, zss, (float*)d_out);
}